// Round 1
// baseline (3347.887 us; speedup 1.0000x reference)
//
#include <hip/hip_runtime.h>
#include <hip/hip_fp16.h>
#include <cstddef>

// Problem dims
#define CI_  64
#define CO_  256
#define DD_  31
#define HH_  96
#define WW_  96
#define HW_  (HH_*WW_)      // 9216
#define DHW_ (DD_*HW_)      // 285696
#define TAPS 27
#define KELEM (CI_*TAPS)    // 1728
#define EPSV 1e-5f

// Conv tiling
#define HT 4
#define WT 16
#define CICH 16
#define HALO_H 6            // HT+2
#define HALO_W 18           // WT+2
#define L_DD 108            // HALO_H*HALO_W
#define L_CI 324            // 3*L_DD
#define LDS_N (CICH*L_CI)   // 5184 floats = 20.7 KB

// -------- weight repack: w[co][ci][kd][kh][kw] -> wt[t][co], t = ci*27+tap --------
__global__ __launch_bounds__(256) void repack_w_k(const float* __restrict__ w,
                                                  float* __restrict__ wt) {
  int idx = blockIdx.x * 256 + threadIdx.x;
  if (idx >= CO_ * KELEM) return;
  int co = idx & 255;
  int t  = idx >> 8;                 // 0..1727, same tap ordering as source layout
  wt[idx] = w[co * KELEM + t];
}

// -------- conv3d + BN(inference) + activation, gates stored as fp16 --------
// grid: x = (W/WT)*(H/HT)=144 tiles, y = D=31, z = gate group g=0..3 (64 co each)
// block: 256 threads = 4 waves; lane = spatial (4h x 16w); wave = 16-co slice.
__global__ __launch_bounds__(256) void conv_bn_act_k(
    const float* __restrict__ x, const float* __restrict__ wt,
    const float* __restrict__ gamma, const float* __restrict__ beta,
    const float* __restrict__ mean, const float* __restrict__ var,
    __half* __restrict__ gates)
{
  __shared__ float xs[LDS_N];

  const int wti = blockIdx.x % (WW_ / WT);
  const int hti = blockIdx.x / (WW_ / WT);
  const int d   = blockIdx.y;
  const int g   = blockIdx.z;
  const int h0  = hti * HT, w0 = wti * WT;

  const int tid  = threadIdx.x;
  const int lane = tid & 63;
  // force wave index wave-uniform so weight loads scalarize (s_load_dwordx16)
  const int wave = __builtin_amdgcn_readfirstlane(tid >> 6);
  const int lw   = lane & 15;   // 0..15 along W
  const int lh   = lane >> 4;   // 0..3  along H
  const int co_base = g * 64 + wave * 16;

  float acc[16];
#pragma unroll
  for (int i = 0; i < 16; i++) acc[i] = 0.f;

  for (int cc = 0; cc < CI_; cc += CICH) {
    __syncthreads();
    // stage x halo tile: xs[ci][dd][row][col] = x[cc+ci][d+dd-1][h0+row-1][w0+col-1]
    for (int i = tid; i < LDS_N; i += 256) {
      int ci  = i / L_CI;
      int r   = i - ci * L_CI;
      int dd  = r / L_DD;
      int r2  = r - dd * L_DD;
      int row = r2 / HALO_W;
      int col = r2 - row * HALO_W;
      int gd = d + dd - 1;
      int gh = h0 + row - 1;
      int gw = w0 + col - 1;
      float v = 0.f;
      if ((unsigned)gd < (unsigned)DD_ && (unsigned)gh < (unsigned)HH_ &&
          (unsigned)gw < (unsigned)WW_)
        v = x[(size_t)(cc + ci) * DHW_ + gd * HW_ + gh * WW_ + gw];
      xs[i] = v;
    }
    __syncthreads();

    const float* wpc = wt + (size_t)(cc * TAPS) * 256 + co_base;
#pragma unroll 1
    for (int ci = 0; ci < CICH; ++ci) {
      const float* xsc = xs + ci * L_CI + lh * HALO_W + lw;
      const float* wp  = wpc + (size_t)ci * TAPS * 256;
#pragma unroll
      for (int kd = 0; kd < 3; kd++)
#pragma unroll
        for (int kh = 0; kh < 3; kh++)
#pragma unroll
          for (int kw = 0; kw < 3; kw++) {
            float xv = xsc[kd * L_DD + kh * HALO_W + kw];
            const float* wv = wp + (kd * 9 + kh * 3 + kw) * 256;
#pragma unroll
            for (int i = 0; i < 16; i++)
              acc[i] = fmaf(wv[i], xv, acc[i]);
          }
    }
  }

  // epilogue: BN + activation (block-uniform branch) + fp16 store
  const int sp = d * HW_ + (h0 + lh) * WW_ + (w0 + lw);
  const bool istanh = (g == 0) || (g == 3);
#pragma unroll
  for (int i = 0; i < 16; i++) {
    int co = co_base + i;
    float s = gamma[co] * rsqrtf(var[co] + EPSV);
    float b = fmaf(-mean[co], s, beta[co]);
    float v = fmaf(acc[i], s, b);
    float a;
    if (istanh) a = tanhf(v);
    else        a = 1.0f / (1.0f + __expf(-v));
    gates[(size_t)co * DHW_ + sp] = __float2half(a);
  }
}

// -------- SRU-style recurrence over D, thread per (c,h,w) --------
__global__ __launch_bounds__(256) void recurrence_k(const __half* __restrict__ gates,
                                                    float* __restrict__ out) {
  int idx = blockIdx.x * 256 + threadIdx.x;
  if (idx >= CI_ * HW_) return;
  int c = idx / HW_;
  int p = idx - c * HW_;
  const __half* gw = gates + (size_t)c * DHW_ + p;          // Wx  (co 0..63)
  const __half* gf = gw + (size_t)64 * DHW_;                // ft  (co 64..127)
  const __half* gr = gw + (size_t)128 * DHW_;               // rt  (co 128..191)
  const __half* gx = gw + (size_t)192 * DHW_;               // X   (co 192..255)
  float* op = out + (size_t)c * DHW_ + p;

  float f0 = __half2float(gf[0]);
  float r0 = __half2float(gr[0]);
  float x0 = __half2float(gx[0]);
  float C = 1.f - f0;
  op[0] = fmaf(r0, C - x0, x0);                  // r*C + (1-r)*x
#pragma unroll 1
  for (int t = 1; t < DD_; t++) {
    float wv = __half2float(gw[(size_t)t * HW_]);
    float f  = __half2float(gf[(size_t)t * HW_]);
    float r  = __half2float(gr[(size_t)t * HW_]);
    float xv = __half2float(gx[(size_t)t * HW_]);
    C = fmaf(f, C - wv, wv);                     // f*C + (1-f)*wx
    op[(size_t)t * HW_] = fmaf(r, C - xv, xv);   // r*C + (1-r)*xx
  }
}

extern "C" void kernel_launch(void* const* d_in, const int* in_sizes, int n_in,
                              void* d_out, int out_size, void* d_ws, size_t ws_size,
                              hipStream_t stream) {
  const float* x     = (const float*)d_in[0];
  const float* w     = (const float*)d_in[1];
  const float* gamma = (const float*)d_in[2];
  const float* beta  = (const float*)d_in[3];
  const float* mean  = (const float*)d_in[4];
  const float* var   = (const float*)d_in[5];
  float* out = (float*)d_out;

  // ws layout: [wt: 1728*256 fp32 = 1.77 MB][gates: 256*285696 fp16 = 146.3 MB]
  float*  wt    = (float*)d_ws;
  __half* gates = (__half*)((char*)d_ws + (size_t)CO_ * KELEM * sizeof(float));

  repack_w_k<<<(CO_ * KELEM + 255) / 256, 256, 0, stream>>>(w, wt);

  dim3 gconv((WW_ / WT) * (HH_ / HT), DD_, 4);
  conv_bn_act_k<<<gconv, 256, 0, stream>>>(x, wt, gamma, beta, mean, var, gates);

  recurrence_k<<<(CI_ * HW_ + 255) / 256, 256, 0, stream>>>(gates, out);
}

// Round 2
// 777.329 us; speedup vs baseline: 4.3069x; 4.3069x over previous
//
#include <hip/hip_runtime.h>
#include <hip/hip_fp16.h>
#include <cstddef>

// Problem dims
#define CI_  64
#define CO_  256
#define DD_  31
#define HH_  96
#define WW_  96
#define HW_  (HH_*WW_)      // 9216
#define DHW_ (DD_*HW_)      // 285696
#define EPSV 1e-5f

// Conv tiling: block tile M=128 spatial (4h x 32w) x N=256 co, 4 waves
#define TLH 4
#define TLW 32
#define HD 3                // kd halo depth
#define HR 6                // TLH+2
#define HC 34               // TLW+2
#define CIC 32              // ci chunk
// LDS layout strides in halves: xh[dd][row][cig(4)][col(34)][ci8(8)]
#define S_COL 8
#define S_CIG 272           // 34*8
#define S_ROW 1088          // 4*272
#define S_DD  6528          // 6*1088
#define XH_N  19584         // 3*6528 halves = 39168 B

typedef _Float16 half8  __attribute__((ext_vector_type(8)));
typedef _Float16 half4v __attribute__((ext_vector_type(4)));
typedef float    float4v __attribute__((ext_vector_type(4)));

// -------- weight repack: w[co][ci][kd][kh][kw] fp32 -> wr[t][co][ci] fp16 --------
__global__ __launch_bounds__(256) void repack_w_k(const float* __restrict__ w,
                                                  _Float16* __restrict__ wr) {
  int idx = blockIdx.x * 256 + threadIdx.x;   // 27*256*64 = 442368
  if (idx >= 27 * 256 * 64) return;
  int ci = idx & 63;
  int co = (idx >> 6) & 255;
  int t  = idx >> 14;
  wr[idx] = (_Float16)w[co * 1728 + ci * 27 + t];
}

// -------- conv3d (implicit GEMM, f16 MFMA) + BN + activation -> fp16 gates ------
// grid: x = 72 (24 h-tiles * 3 w-tiles), y = 31 (d). block 256 = 4 waves.
// wave w computes all 128 spatial x co [64w..64w+63] -> one gate group per wave.
__global__ __launch_bounds__(256, 2) void conv_mfma_k(
    const float* __restrict__ x, const _Float16* __restrict__ wr,
    const float* __restrict__ gamma, const float* __restrict__ beta,
    const float* __restrict__ mean, const float* __restrict__ var,
    _Float16* __restrict__ gates)
{
  __shared__ _Float16 xh[XH_N];

  const int wti = blockIdx.x % 3;
  const int hti = blockIdx.x / 3;
  const int d   = blockIdx.y;
  const int h0  = hti * TLH, w0 = wti * TLW;

  const int tid  = threadIdx.x;
  const int lane = tid & 63;
  const int wave = __builtin_amdgcn_readfirstlane(tid >> 6);
  const int lw   = lane & 15;    // A: m(spatial-w)  B: n(co)  both lane&15
  const int cig  = lane >> 4;    // k-group (8 consecutive ci each)

  float4v acc[8][4];
#pragma unroll
  for (int m = 0; m < 8; m++)
#pragma unroll
    for (int j = 0; j < 4; j++) acc[m][j] = (float4v)0.f;

  for (int cc = 0; cc < CI_; cc += CIC) {
    __syncthreads();
    // ---- stage halo tile, fp32->fp16, transpose to ci-innermost ----
    // task i -> (cg4, dd, row, col): 4 consecutive ci -> one 8B ds_write
    for (int i = tid; i < 3 * 6 * 34 * 8; i += 256) {
      int cg4 = i / 612;                 // 0..7 (ci quad)
      int r   = i - cg4 * 612;
      int dd  = r / 204;
      int r2  = r - dd * 204;
      int row = r2 / 34;
      int col = r2 - row * 34;
      int gd = d + dd - 1, gh = h0 + row - 1, gw = w0 + col - 1;
      bool ok = (unsigned)gd < (unsigned)DD_ && (unsigned)gh < (unsigned)HH_ &&
                (unsigned)gw < (unsigned)WW_;
      const float* xp = x + (size_t)(cc + cg4 * 4) * DHW_ + gd * HW_ + gh * WW_ + gw;
      half4v hv;
#pragma unroll
      for (int j = 0; j < 4; j++)
        hv[j] = ok ? (_Float16)xp[(size_t)j * DHW_] : (_Float16)0.f;
      int a = dd * S_DD + row * S_ROW + (cg4 >> 1) * S_CIG + col * S_COL + (cg4 & 1) * 4;
      *(half4v*)(xh + a) = hv;
    }
    __syncthreads();

    // ---- K-loop over 27 taps, MFMA k=32 covers the whole ci chunk ----
#pragma unroll 1
    for (int kd = 0; kd < 3; kd++)
#pragma unroll 1
      for (int kh = 0; kh < 3; kh++)
#pragma unroll 1
        for (int kw = 0; kw < 3; kw++) {
          const int t = kd * 9 + kh * 3 + kw;
          // B fragments: wr[t][co][ci], lane: co=..+lw, ci=cc+cig*8 (16B)
          const _Float16* bp = wr + (((size_t)t * 256 + wave * 64 + lw) * 64 + cc + cig * 8);
          half8 bf[4];
#pragma unroll
          for (int j = 0; j < 4; j++) bf[j] = *(const half8*)(bp + (size_t)j * 16 * 64);
          // A fragments: one ds_read_b128 per m-tile
          const int abase = kd * S_DD + kh * S_ROW + cig * S_CIG + (lw + kw) * S_COL;
          half8 af[8];
#pragma unroll
          for (int m = 0; m < 8; m++)
            af[m] = *(const half8*)(xh + abase + (m >> 1) * S_ROW + (m & 1) * 128);
#pragma unroll
          for (int m = 0; m < 8; m++)
#pragma unroll
            for (int j = 0; j < 4; j++)
              acc[m][j] = __builtin_amdgcn_mfma_f32_16x16x32_f16(af[m], bf[j], acc[m][j], 0, 0, 0);
        }
  }

  // ---- epilogue: BN + activation (wave-uniform), pack 4 halves along w ----
  const bool istanh = (wave == 0) || (wave == 3);
#pragma unroll 1
  for (int j = 0; j < 4; j++) {
    const int co = wave * 64 + j * 16 + lw;       // D: n = lane&15
    const float s  = gamma[co] * rsqrtf(var[co] + EPSV);
    const float bb = fmaf(-mean[co], s, beta[co]);
    _Float16* gbase = gates + (size_t)co * DHW_ + d * HW_;
#pragma unroll
    for (int m = 0; m < 8; m++) {
      half4v hv;
#pragma unroll
      for (int reg = 0; reg < 4; reg++) {
        float v = fmaf(acc[m][j][reg], s, bb);
        float a;
        if (istanh) {
          float tt = __expf(-2.f * fabsf(v));
          float r  = (1.f - tt) * __builtin_amdgcn_rcpf(1.f + tt);
          a = copysignf(r, v);
        } else {
          a = __builtin_amdgcn_rcpf(1.f + __expf(-v));
        }
        hv[reg] = (_Float16)a;
      }
      // D row m_idx = (lane>>4)*4+reg -> w_local = (m&1)*16 + (lane>>4)*4 + reg
      int addr = (h0 + (m >> 1)) * WW_ + w0 + (m & 1) * 16 + (lane >> 4) * 4;
      *(half4v*)(gbase + addr) = hv;
    }
  }
}

// -------- SRU-style recurrence over D, thread per (c,h,w) --------
__global__ __launch_bounds__(256) void recurrence_k(const __half* __restrict__ gates,
                                                    float* __restrict__ out) {
  int idx = blockIdx.x * 256 + threadIdx.x;
  if (idx >= CI_ * HW_) return;
  int c = idx / HW_;
  int p = idx - c * HW_;
  const __half* gw = gates + (size_t)c * DHW_ + p;          // Wx  (co 0..63)
  const __half* gf = gw + (size_t)64 * DHW_;                // ft
  const __half* gr = gw + (size_t)128 * DHW_;               // rt
  const __half* gx = gw + (size_t)192 * DHW_;               // X
  float* op = out + (size_t)c * DHW_ + p;

  float f0 = __half2float(gf[0]);
  float r0 = __half2float(gr[0]);
  float x0 = __half2float(gx[0]);
  float C = 1.f - f0;
  op[0] = fmaf(r0, C - x0, x0);
#pragma unroll 1
  for (int t = 1; t < DD_; t++) {
    float wv = __half2float(gw[(size_t)t * HW_]);
    float f  = __half2float(gf[(size_t)t * HW_]);
    float r  = __half2float(gr[(size_t)t * HW_]);
    float xv = __half2float(gx[(size_t)t * HW_]);
    C = fmaf(f, C - wv, wv);
    op[(size_t)t * HW_] = fmaf(r, C - xv, xv);
  }
}

extern "C" void kernel_launch(void* const* d_in, const int* in_sizes, int n_in,
                              void* d_out, int out_size, void* d_ws, size_t ws_size,
                              hipStream_t stream) {
  const float* x     = (const float*)d_in[0];
  const float* w     = (const float*)d_in[1];
  const float* gamma = (const float*)d_in[2];
  const float* beta  = (const float*)d_in[3];
  const float* mean  = (const float*)d_in[4];
  const float* var   = (const float*)d_in[5];
  float* out = (float*)d_out;

  // ws: [wr: 27*256*64 fp16 = 884736 B][align 256][gates: 256*285696 fp16]
  _Float16* wr    = (_Float16*)d_ws;
  _Float16* gates = (_Float16*)((char*)d_ws + ((27 * 256 * 64 * 2 + 255) & ~255));

  repack_w_k<<<(27 * 256 * 64 + 255) / 256, 256, 0, stream>>>(w, wr);

  dim3 gconv(72, DD_);
  conv_mfma_k<<<gconv, 256, 0, stream>>>(x, wr, gamma, beta, mean, var, gates);

  recurrence_k<<<(CI_ * HW_ + 255) / 256, 256, 0, stream>>>((const __half*)gates, out);
}